// Round 12
// baseline (108.370 us; speedup 1.0000x reference)
//
#include <hip/hip_runtime.h>

// Multi-Scale Deformable Attention forward, fp32.
// B=1, Q=19947, heads=8, D=32, L=4, P=4.
// Levels: (100,150),(50,75),(25,38),(13,19); starts 0,15000,18750,19700.
//
// - Head-per-XCD: blockIdx.x%8 == head rides round-robin XCD dispatch;
//   per-head value slice (2.55 MB) resident in the XCD's 4 MiB L2
//   (verified: FETCH_SIZE 315->30 MB).
// - Metadata dedup WITHOUT LDS (R11 lesson: LDS round-trip + occupancy
//   cost regressed): lane j of each 8-lane pair-group computes the
//   bilinear coefficients/indices for samples 2j,2j+1 only; phase 2
//   broadcasts them via __shfl(width=8) register shuffles.
// - f32x4 accumulator + vector FMAs to encourage v_pk_fma_f32.

typedef float f32x4 __attribute__((ext_vector_type(4)));
typedef float f32x2 __attribute__((ext_vector_type(2)));

constexpr int HEADS = 8;
constexpr int DCH   = 32;
constexpr int NSP   = 16;      // L*P samples per (q,h)
constexpr int NQ    = 19947;
constexpr int QPB   = 32;      // pairs per block (256 thr / 8 lanes)

__global__ __launch_bounds__(256)
void msda_fwd_kernel(const float* __restrict__ value,
                     const float* __restrict__ loc,
                     const float* __restrict__ attw,
                     float* __restrict__ out)
{
    const int h    = blockIdx.x & 7;          // head == XCD id
    const int qblk = blockIdx.x >> 3;
    const int t    = threadIdx.x;
    const int grp  = t >> 3;                  // pair within block
    const int j    = t & 7;                   // lane in group; owns samples 2j,2j+1
    const int q    = qblk * QPB + grp;
    const int pair = q * HEADS + h;

    // ---- phase 1: this lane's 2 samples' metadata (coalesced loads) ----
    float cA0 = 0.f, cA1 = 0.f, cA2 = 0.f, cA3 = 0.f;
    float cB0 = 0.f, cB1 = 0.f, cB2 = 0.f, cB3 = 0.f;
    int   iA0 = 0, iA1 = 0, iA2 = 0, iA3 = 0;
    int   iB0 = 0, iB1 = 0, iB2 = 0, iB3 = 0;

    if (q < NQ) {
        const f32x4 xy = __builtin_nontemporal_load(
            (const f32x4*)(loc + (size_t)pair * (NSP * 2) + j * 4));
        const f32x2 aw2 = __builtin_nontemporal_load(
            (const f32x2*)(attw + (size_t)pair * NSP + j * 2));

        const int l = j >> 1;                 // both owned samples share a level
        const float fW = (l == 0) ? 150.f : (l == 1) ? 75.f : (l == 2) ? 38.f : 19.f;
        const float fH = (l == 0) ? 100.f : (l == 1) ? 50.f : (l == 2) ? 25.f : 13.f;
        const int   W  = (l == 0) ? 150   : (l == 1) ? 75   : (l == 2) ? 38   : 19;
        const int   H  = (l == 0) ? 100   : (l == 1) ? 50   : (l == 2) ? 25   : 13;
        const int   S  = (l == 0) ? 0     : (l == 1) ? 15000: (l == 2) ? 18750: 19700;

        auto meta = [&](float lx, float ly, float aw,
                        float& c0, float& c1, float& c2, float& c3,
                        int& i0, int& i1, int& i2, int& i3) {
            const float x = lx * fW - 0.5f;
            const float y = ly * fH - 0.5f;
            const float x0f = floorf(x);
            const float y0f = floorf(y);
            const float wx1 = x - x0f;
            const float wy1 = y - y0f;
            const float wx0 = 1.f - wx1;
            const float wy0 = 1.f - wy1;
            const int x0 = (int)x0f, y0 = (int)y0f;
            const int x1 = x0 + 1,   y1 = y0 + 1;
            const bool vx0 = (x0 >= 0) & (x0 < W);
            const bool vx1 = (x1 >= 0) & (x1 < W);
            const bool vy0 = (y0 >= 0) & (y0 < H);
            const bool vy1 = (y1 >= 0) & (y1 < H);
            const int cx0 = min(max(x0, 0), W - 1);
            const int cx1 = min(max(x1, 0), W - 1);
            const int cy0 = min(max(y0, 0), H - 1);
            const int cy1 = min(max(y1, 0), H - 1);
            c0 = aw * wx0 * wy0 * ((vx0 && vy0) ? 1.f : 0.f);
            c1 = aw * wx1 * wy0 * ((vx1 && vy0) ? 1.f : 0.f);
            c2 = aw * wx0 * wy1 * ((vx0 && vy1) ? 1.f : 0.f);
            c3 = aw * wx1 * wy1 * ((vx1 && vy1) ? 1.f : 0.f);
            const int r0 = S + cy0 * W;
            const int r1 = S + cy1 * W;
            i0 = r0 + cx0; i1 = r0 + cx1; i2 = r1 + cx0; i3 = r1 + cx1;
        };
        meta(xy.x, xy.y, aw2.x, cA0, cA1, cA2, cA3, iA0, iA1, iA2, iA3);
        meta(xy.z, xy.w, aw2.y, cB0, cB1, cB2, cB3, iB0, iB1, iB2, iB3);
    }

    // ---- phase 2: shuffle-broadcast + gather + vector FMA ----
    const float* vbase = value + h * DCH + j * 4;   // token stride = 256 floats
    f32x4 acc = {0.f, 0.f, 0.f, 0.f};

#pragma unroll
    for (int sp = 0; sp < NSP; ++sp) {
        const int  owner = sp >> 1;
        const bool useB  = (sp & 1) != 0;           // compile-time after unroll

        const float c0 = __shfl(useB ? cB0 : cA0, owner, 8);
        const float c1 = __shfl(useB ? cB1 : cA1, owner, 8);
        const float c2 = __shfl(useB ? cB2 : cA2, owner, 8);
        const float c3 = __shfl(useB ? cB3 : cA3, owner, 8);
        const int   i0 = __shfl(useB ? iB0 : iA0, owner, 8);
        const int   i1 = __shfl(useB ? iB1 : iA1, owner, 8);
        const int   i2 = __shfl(useB ? iB2 : iA2, owner, 8);
        const int   i3 = __shfl(useB ? iB3 : iA3, owner, 8);

        const f32x4 g00 = *(const f32x4*)(vbase + ((size_t)i0 << 8));
        const f32x4 g01 = *(const f32x4*)(vbase + ((size_t)i1 << 8));
        const f32x4 g10 = *(const f32x4*)(vbase + ((size_t)i2 << 8));
        const f32x4 g11 = *(const f32x4*)(vbase + ((size_t)i3 << 8));

        acc += g00 * c0;
        acc += g01 * c1;
        acc += g10 * c2;
        acc += g11 * c3;
    }

    if (q < NQ) {
        __builtin_nontemporal_store(acc, (f32x4*)(out + (size_t)pair * DCH + j * 4));
    }
}

extern "C" void kernel_launch(void* const* d_in, const int* in_sizes, int n_in,
                              void* d_out, int out_size, void* d_ws, size_t ws_size,
                              hipStream_t stream) {
    const float* value = (const float*)d_in[0];
    const float* loc   = (const float*)d_in[3];
    const float* attw  = (const float*)d_in[4];
    float* out = (float*)d_out;

    const int qblocks = (NQ + QPB - 1) / QPB;    // 624
    const int grid = qblocks * HEADS;            // 4992
    msda_fwd_kernel<<<grid, 256, 0, stream>>>(value, loc, attw, out);
}

// Round 13
// 71.251 us; speedup vs baseline: 1.5210x; 1.5210x over previous
//
#include <hip/hip_runtime.h>

// Multi-Scale Deformable Attention forward, fp32 in/out.
// B=1, Q=19947, heads=8, D=32, L=4, P=4.
// Levels: (100,150),(50,75),(25,38),(13,19); starts 0,15000,18750,19700.
//
// - Head-per-XCD: blockIdx.x%8 == head rides round-robin XCD dispatch;
//   per-head value slice resident in the XCD's 4 MiB L2 (FETCH 315->30 MB).
// - R10 structure (proven 60 us): LDS-staged loc/attw metadata, redundant
//   per-lane metadata compute (free latency filler; dedup via LDS meta or
//   shfl both regressed, R11/R12).
// - NEW: value converted once to fp16 in d_ws; gather rows become one
//   64 B cache line instead of two -> halves L2 gather bytes and TA line
//   touches (the measured bound). Host falls back to fp32 gathers if
//   ws_size < 10.2 MB (decision depends only on ws_size -> deterministic).

typedef float    f32x4 __attribute__((ext_vector_type(4)));
typedef _Float16 f16x4 __attribute__((ext_vector_type(4)));

constexpr int HEADS = 8;
constexpr int DCH   = 32;
constexpr int LVLS  = 4;
constexpr int PTS   = 4;
constexpr int NSP   = LVLS * PTS;
constexpr int NQ    = 19947;
constexpr int QPB   = 32;    // query pairs per block (256 thr / 8 lanes)
constexpr int NVAL  = NQ * HEADS * DCH;   // 5,106,432 floats

// ---- pre-pass: fp32 value -> fp16 copy in ws --------------------------------
__global__ __launch_bounds__(256)
void cvt_f16_kernel(const float* __restrict__ value, _Float16* __restrict__ ws)
{
    const int i8 = (blockIdx.x * 256 + threadIdx.x) * 8;
    if (i8 >= NVAL) return;
    const f32x4 a = __builtin_nontemporal_load((const f32x4*)(value + i8));
    const f32x4 b = __builtin_nontemporal_load((const f32x4*)(value + i8 + 4));
    f16x4 ha = __builtin_convertvector(a, f16x4);
    f16x4 hb = __builtin_convertvector(b, f16x4);
    *(f16x4*)(ws + i8)     = ha;   // keep in L2 (no nt): gathers read it next
    *(f16x4*)(ws + i8 + 4) = hb;
}

// ---- main kernel, templated on value dtype ---------------------------------
template <bool F16>
__global__ __launch_bounds__(256)
void msda_fwd_kernel(const void* __restrict__ valuev,
                     const float* __restrict__ loc,
                     const float* __restrict__ attw,
                     float* __restrict__ out)
{
    __shared__ float s_loc[QPB][33];
    __shared__ float s_aw [QPB][17];

    const int h    = blockIdx.x & 7;          // head == XCD id
    const int qblk = blockIdx.x >> 3;
    const int q0   = qblk * QPB;
    const int t    = threadIdx.x;

    // ---- cooperative metadata staging (coalesced, once) ----
    {
        const int sub = t >> 3, j = t & 7;
        const int q = q0 + sub;
        if (q < NQ) {
            const f32x4 v = __builtin_nontemporal_load(
                (const f32x4*)(loc + ((size_t)(q * HEADS + h)) * (NSP * 2) + j * 4));
            s_loc[sub][j * 4 + 0] = v.x;
            s_loc[sub][j * 4 + 1] = v.y;
            s_loc[sub][j * 4 + 2] = v.z;
            s_loc[sub][j * 4 + 3] = v.w;
        }
        if (t < 128) {
            const int sub2 = t >> 2, j2 = t & 3;
            const int q2 = q0 + sub2;
            if (q2 < NQ) {
                const f32x4 w = __builtin_nontemporal_load(
                    (const f32x4*)(attw + ((size_t)(q2 * HEADS + h)) * NSP + j2 * 4));
                s_aw[sub2][j2 * 4 + 0] = w.x;
                s_aw[sub2][j2 * 4 + 1] = w.y;
                s_aw[sub2][j2 * 4 + 2] = w.z;
                s_aw[sub2][j2 * 4 + 3] = w.w;
            }
        }
    }
    __syncthreads();

    const int sub = t >> 3;
    const int d0  = (t & 7) * 4;
    const int q   = q0 + sub;
    if (q >= NQ) return;
    const int pair = q * HEADS + h;

    const int lvlH[LVLS] = {100, 50, 25, 13};
    const int lvlW[LVLS] = {150, 75, 38, 19};
    const int lvlS[LVLS] = {0, 15000, 18750, 19700};

    // token stride = 256 elements in both layouts ( <<8 )
    const float*    vf32 = (const float*)valuev    + h * DCH + d0;
    const _Float16* vf16 = (const _Float16*)valuev + h * DCH + d0;

    f32x4 acc = {0.f, 0.f, 0.f, 0.f};

#pragma unroll
    for (int l = 0; l < LVLS; ++l) {
        const int H = lvlH[l], W = lvlW[l], S = lvlS[l];
        const float fH = (float)H, fW = (float)W;
#pragma unroll
        for (int p = 0; p < PTS; ++p) {
            const int sp = l * PTS + p;
            const float lx = s_loc[sub][sp * 2 + 0];
            const float ly = s_loc[sub][sp * 2 + 1];
            const float aw = s_aw[sub][sp];

            const float x = lx * fW - 0.5f;
            const float y = ly * fH - 0.5f;
            const float x0f = floorf(x);
            const float y0f = floorf(y);
            const float wx1 = x - x0f;
            const float wy1 = y - y0f;
            const float wx0 = 1.f - wx1;
            const float wy0 = 1.f - wy1;

            const int x0 = (int)x0f, y0 = (int)y0f;
            const int x1 = x0 + 1,   y1 = y0 + 1;

            const bool vx0 = (x0 >= 0) & (x0 < W);
            const bool vx1 = (x1 >= 0) & (x1 < W);
            const bool vy0 = (y0 >= 0) & (y0 < H);
            const bool vy1 = (y1 >= 0) & (y1 < H);

            const int cx0 = min(max(x0, 0), W - 1);
            const int cx1 = min(max(x1, 0), W - 1);
            const int cy0 = min(max(y0, 0), H - 1);
            const int cy1 = min(max(y1, 0), H - 1);

            const float c00 = aw * wx0 * wy0 * ((vx0 && vy0) ? 1.f : 0.f);
            const float c01 = aw * wx1 * wy0 * ((vx1 && vy0) ? 1.f : 0.f);
            const float c10 = aw * wx0 * wy1 * ((vx0 && vy1) ? 1.f : 0.f);
            const float c11 = aw * wx1 * wy1 * ((vx1 && vy1) ? 1.f : 0.f);

            const int r0 = S + cy0 * W;
            const int r1 = S + cy1 * W;
            const size_t i00 = (size_t)(r0 + cx0) << 8;
            const size_t i01 = (size_t)(r0 + cx1) << 8;
            const size_t i10 = (size_t)(r1 + cx0) << 8;
            const size_t i11 = (size_t)(r1 + cx1) << 8;

            f32x4 g00, g01, g10, g11;
            if constexpr (F16) {
                g00 = __builtin_convertvector(*(const f16x4*)(vf16 + i00), f32x4);
                g01 = __builtin_convertvector(*(const f16x4*)(vf16 + i01), f32x4);
                g10 = __builtin_convertvector(*(const f16x4*)(vf16 + i10), f32x4);
                g11 = __builtin_convertvector(*(const f16x4*)(vf16 + i11), f32x4);
            } else {
                g00 = *(const f32x4*)(vf32 + i00);
                g01 = *(const f32x4*)(vf32 + i01);
                g10 = *(const f32x4*)(vf32 + i10);
                g11 = *(const f32x4*)(vf32 + i11);
            }

            acc += g00 * c00;
            acc += g01 * c01;
            acc += g10 * c10;
            acc += g11 * c11;
        }
    }

    __builtin_nontemporal_store(acc, (f32x4*)(out + (size_t)pair * DCH + d0));
}

extern "C" void kernel_launch(void* const* d_in, const int* in_sizes, int n_in,
                              void* d_out, int out_size, void* d_ws, size_t ws_size,
                              hipStream_t stream) {
    const float* value = (const float*)d_in[0];
    const float* loc   = (const float*)d_in[3];
    const float* attw  = (const float*)d_in[4];
    float* out = (float*)d_out;

    const int qblocks = (NQ + QPB - 1) / QPB;    // 624
    const int grid = qblocks * HEADS;            // 4992

    const size_t f16_bytes = (size_t)NVAL * sizeof(_Float16);  // 10.2 MB
    if (ws_size >= f16_bytes) {
        _Float16* ws = (_Float16*)d_ws;
        const int cgrid = (NVAL / 8 + 255) / 256;
        cvt_f16_kernel<<<cgrid, 256, 0, stream>>>(value, ws);
        msda_fwd_kernel<true><<<grid, 256, 0, stream>>>(ws, loc, attw, out);
    } else {
        msda_fwd_kernel<false><<<grid, 256, 0, stream>>>(value, loc, attw, out);
    }
}

// Round 14
// 54.438 us; speedup vs baseline: 1.9907x; 1.3088x over previous
//
#include <hip/hip_runtime.h>

// Multi-Scale Deformable Attention forward, fp32 in/out.
// B=1, Q=19947, heads=8, D=32, L=4, P=4.
// Levels: (100,150),(50,75),(25,38),(13,19); starts 0,15000,18750,19700.
//
// - Head-per-XCD: blockIdx.x%8 == head rides round-robin XCD dispatch.
// - Pre-pass converts value to fp16 AND transposes to head-major
//   [h][token][32ch] in d_ws: per-XCD slice = 1.28 MB (fully L2-resident,
//   no cross-head line pollution); each corner row = one 64 B line.
// - 4 lanes per (q,h) pair, 8 ch/lane: half the threads of R13 -> total
//   metadata VALU halves (4x redundancy), load insts halve; FMAs written
//   scalar as acc += c*(float)g[k] to fuse into v_fma_mix_f32.
// - LDS-staged loc/attw (R10, proven); dedup-by-communication rejected
//   (R11 LDS-meta, R12 shfl both regressed).

typedef float    f32x4 __attribute__((ext_vector_type(4)));
typedef float    f32x8 __attribute__((ext_vector_type(8)));
typedef _Float16 f16x8 __attribute__((ext_vector_type(8)));

constexpr int HEADS = 8;
constexpr int DCH   = 32;
constexpr int LVLS  = 4;
constexpr int PTS   = 4;
constexpr int NSP   = LVLS * PTS;
constexpr int NQ    = 19947;
constexpr int QPB   = 64;              // pairs per block (256 thr / 4 lanes)
constexpr int HSTR  = NQ * DCH;        // halves per head slice (638,304)
constexpr int NVAL  = NQ * HEADS * DCH;

// ---- pre-pass: fp32 [tok][head][ch] -> fp16 head-major [head][tok][ch] -----
__global__ __launch_bounds__(256)
void cvt_kernel(const float* __restrict__ value, _Float16* __restrict__ ws)
{
    const int i = blockIdx.x * 256 + threadIdx.x;   // item = 8 channels
    if (i >= NQ * HEADS * 4) return;
    const int c8 = i & 3;
    const int h  = (i >> 2) & 7;
    const int t  = i >> 5;
    const float* src = value + (size_t)t * 256 + h * 32 + c8 * 8;
    const f32x4 a = __builtin_nontemporal_load((const f32x4*)src);
    const f32x4 b = __builtin_nontemporal_load((const f32x4*)(src + 4));
    const f32x8 v = {a.x, a.y, a.z, a.w, b.x, b.y, b.z, b.w};
    const f16x8 o = __builtin_convertvector(v, f16x8);
    *(f16x8*)(ws + (size_t)h * HSTR + t * 32 + c8 * 8) = o;   // stays in L2
}

// ---- main kernel -----------------------------------------------------------
template <bool F16>
__global__ __launch_bounds__(256)
void msda_fwd_kernel(const void* __restrict__ valuev,
                     const float* __restrict__ loc,
                     const float* __restrict__ attw,
                     float* __restrict__ out)
{
    __shared__ float s_loc[QPB][33];   // 8.4 KB
    __shared__ float s_aw [QPB][17];   // 4.4 KB

    const int h    = blockIdx.x & 7;          // head == XCD id
    const int qblk = blockIdx.x >> 3;
    const int q0   = qblk * QPB;
    const int t    = threadIdx.x;

    // ---- cooperative metadata staging (coalesced) ----
#pragma unroll
    for (int it = 0; it < 2; ++it) {
        const int idx = t + it * 256;          // 0..511 loc chunks
        const int sub = idx >> 3, j = idx & 7;
        const int q = q0 + sub;
        if (q < NQ) {
            const f32x4 v = __builtin_nontemporal_load(
                (const f32x4*)(loc + ((size_t)(q * HEADS + h)) * (NSP * 2) + j * 4));
            s_loc[sub][j * 4 + 0] = v.x;
            s_loc[sub][j * 4 + 1] = v.y;
            s_loc[sub][j * 4 + 2] = v.z;
            s_loc[sub][j * 4 + 3] = v.w;
        }
    }
    {
        const int sub = t >> 2, j = t & 3;     // 256 attw chunks
        const int q = q0 + sub;
        if (q < NQ) {
            const f32x4 w = __builtin_nontemporal_load(
                (const f32x4*)(attw + ((size_t)(q * HEADS + h)) * NSP + j * 4));
            s_aw[sub][j * 4 + 0] = w.x;
            s_aw[sub][j * 4 + 1] = w.y;
            s_aw[sub][j * 4 + 2] = w.z;
            s_aw[sub][j * 4 + 3] = w.w;
        }
    }
    __syncthreads();

    const int sub = t >> 2;               // pair in block, 0..63
    const int j   = t & 3;                // channel group, 8 ch each
    const int q   = q0 + sub;
    if (q >= NQ) return;

    const int lvlH[LVLS] = {100, 50, 25, 13};
    const int lvlW[LVLS] = {150, 75, 38, 19};
    const int lvlS[LVLS] = {0, 15000, 18750, 19700};

    const _Float16* vf16 = (const _Float16*)valuev + (size_t)h * HSTR + j * 8;
    const float*    vf32 = (const float*)valuev + h * DCH + j * 8;

    f32x8 acc = {0.f, 0.f, 0.f, 0.f, 0.f, 0.f, 0.f, 0.f};

#pragma unroll
    for (int l = 0; l < LVLS; ++l) {
        const int H = lvlH[l], W = lvlW[l], S = lvlS[l];
        const float fH = (float)H, fW = (float)W;
#pragma unroll
        for (int p = 0; p < PTS; ++p) {
            const int sp = l * PTS + p;
            const float lx = s_loc[sub][sp * 2 + 0];
            const float ly = s_loc[sub][sp * 2 + 1];
            const float aw = s_aw[sub][sp];

            const float x = lx * fW - 0.5f;
            const float y = ly * fH - 0.5f;
            const float x0f = floorf(x);
            const float y0f = floorf(y);
            const float wx1 = x - x0f;
            const float wy1 = y - y0f;
            const float wx0 = 1.f - wx1;
            const float wy0 = 1.f - wy1;

            const int x0 = (int)x0f, y0 = (int)y0f;
            const int x1 = x0 + 1,   y1 = y0 + 1;

            const bool vx0 = (x0 >= 0) & (x0 < W);
            const bool vx1 = (x1 >= 0) & (x1 < W);
            const bool vy0 = (y0 >= 0) & (y0 < H);
            const bool vy1 = (y1 >= 0) & (y1 < H);

            const int cx0 = min(max(x0, 0), W - 1);
            const int cx1 = min(max(x1, 0), W - 1);
            const int cy0 = min(max(y0, 0), H - 1);
            const int cy1 = min(max(y1, 0), H - 1);

            const float c00 = aw * wx0 * wy0 * ((vx0 && vy0) ? 1.f : 0.f);
            const float c01 = aw * wx1 * wy0 * ((vx1 && vy0) ? 1.f : 0.f);
            const float c10 = aw * wx0 * wy1 * ((vx0 && vy1) ? 1.f : 0.f);
            const float c11 = aw * wx1 * wy1 * ((vx1 && vy1) ? 1.f : 0.f);

            const int r0 = S + cy0 * W;
            const int r1 = S + cy1 * W;
            const int i00 = r0 + cx0;
            const int i01 = r0 + cx1;
            const int i10 = r1 + cx0;
            const int i11 = r1 + cx1;

            if constexpr (F16) {
                const f16x8 g00 = *(const f16x8*)(vf16 + (size_t)i00 * 32);
                const f16x8 g01 = *(const f16x8*)(vf16 + (size_t)i01 * 32);
                const f16x8 g10 = *(const f16x8*)(vf16 + (size_t)i10 * 32);
                const f16x8 g11 = *(const f16x8*)(vf16 + (size_t)i11 * 32);
#pragma unroll
                for (int k = 0; k < 8; ++k) {
                    acc[k] += c00 * (float)g00[k];
                    acc[k] += c01 * (float)g01[k];
                    acc[k] += c10 * (float)g10[k];
                    acc[k] += c11 * (float)g11[k];
                }
            } else {
                const f32x4 a0 = *(const f32x4*)(vf32 + ((size_t)i00 << 8));
                const f32x4 a1 = *(const f32x4*)(vf32 + ((size_t)i00 << 8) + 4);
                const f32x4 b0 = *(const f32x4*)(vf32 + ((size_t)i01 << 8));
                const f32x4 b1 = *(const f32x4*)(vf32 + ((size_t)i01 << 8) + 4);
                const f32x4 c0 = *(const f32x4*)(vf32 + ((size_t)i10 << 8));
                const f32x4 c1 = *(const f32x4*)(vf32 + ((size_t)i10 << 8) + 4);
                const f32x4 d0_ = *(const f32x4*)(vf32 + ((size_t)i11 << 8));
                const f32x4 d1 = *(const f32x4*)(vf32 + ((size_t)i11 << 8) + 4);
#pragma unroll
                for (int k = 0; k < 4; ++k) {
                    acc[k]     += c00 * a0[k] + c01 * b0[k] + c10 * c0[k] + c11 * d0_[k];
                    acc[k + 4] += c00 * a1[k] + c01 * b1[k] + c10 * c1[k] + c11 * d1[k];
                }
            }
        }
    }

    float* op = out + (size_t)(q * HEADS + h) * DCH + j * 8;
    const f32x4 lo = {acc[0], acc[1], acc[2], acc[3]};
    const f32x4 hi = {acc[4], acc[5], acc[6], acc[7]};
    __builtin_nontemporal_store(lo, (f32x4*)op);
    __builtin_nontemporal_store(hi, (f32x4*)(op + 4));
}

extern "C" void kernel_launch(void* const* d_in, const int* in_sizes, int n_in,
                              void* d_out, int out_size, void* d_ws, size_t ws_size,
                              hipStream_t stream) {
    const float* value = (const float*)d_in[0];
    const float* loc   = (const float*)d_in[3];
    const float* attw  = (const float*)d_in[4];
    float* out = (float*)d_out;

    const int qblocks = (NQ + QPB - 1) / QPB;    // 312
    const int grid = qblocks * HEADS;            // 2496

    const size_t f16_bytes = (size_t)NVAL * sizeof(_Float16);  // 10.2 MB
    if (ws_size >= f16_bytes) {
        _Float16* ws = (_Float16*)d_ws;
        const int cgrid = (NQ * HEADS * 4 + 255) / 256;
        cvt_kernel<<<cgrid, 256, 0, stream>>>(value, ws);
        msda_fwd_kernel<true><<<grid, 256, 0, stream>>>(ws, loc, attw, out);
    } else {
        msda_fwd_kernel<false><<<grid, 256, 0, stream>>>(value, loc, attw, out);
    }
}